// Round 14
// baseline (98.879 us; speedup 1.0000x reference)
//
#include <hip/hip_runtime.h>
#include <stdint.h>
#include <math.h>

#define HD 512
#define ID 1408
#define NTOK 2048
#define NPAIRS 4096
#define PADCAP 5120
#define SHOFF 5120
#define TOTROWS 7168

typedef unsigned short u16;
typedef __attribute__((ext_vector_type(8))) __bf16 bf16x8;
typedef __attribute__((ext_vector_type(4))) float f32x4;

__device__ __forceinline__ u16 f2bf(float f) {
  union { float f; uint32_t u; } v; v.f = f;
  uint32_t u = v.u;
  u += 0x7FFFu + ((u >> 16) & 1u);   // RNE
  return (u16)(u >> 16);
}
__device__ __forceinline__ float bf2f(u16 u) {
  union { uint32_t u; float f; } v; v.u = ((uint32_t)u) << 16; return v.f;
}

__device__ __forceinline__ void gll16(const void* g, void* l) {
  __builtin_amdgcn_global_load_lds((const __attribute__((address_space(1))) void*)g,
                                   (__attribute__((address_space(3))) void*)l, 16, 0, 0);
}

// ------------- gate: fp32 logits, softmax, top-2; fused x->bf16 cast -------------
__global__ __launch_bounds__(256) void gate_kernel(
    const float* __restrict__ x, const float* __restrict__ gw,
    u16* __restrict__ xg, float* __restrict__ scores,
    float* __restrict__ topw, int* __restrict__ topidx) {
  int t = blockIdx.x * 4 + (threadIdx.x >> 6);
  int lane = threadIdx.x & 63;
  const float4* xp = (const float4*)(x + (size_t)t * HD + lane * 8);
  float4 v0 = xp[0], v1 = xp[1];
  float xv[8] = {v0.x, v0.y, v0.z, v0.w, v1.x, v1.y, v1.z, v1.w};
  ushort4 o0, o1;
  o0.x = f2bf(xv[0]); o0.y = f2bf(xv[1]); o0.z = f2bf(xv[2]); o0.w = f2bf(xv[3]);
  o1.x = f2bf(xv[4]); o1.y = f2bf(xv[5]); o1.z = f2bf(xv[6]); o1.w = f2bf(xv[7]);
  ushort4* xo = (ushort4*)(xg + (size_t)t * HD + lane * 8);
  xo[0] = o0; xo[1] = o1;
  float sc[8];
#pragma unroll
  for (int e = 0; e < 8; ++e) {
    const float4* gp = (const float4*)(gw + e * HD + lane * 8);
    float4 g0 = gp[0], g1 = gp[1];
    float p = xv[0] * g0.x + xv[1] * g0.y + xv[2] * g0.z + xv[3] * g0.w
            + xv[4] * g1.x + xv[5] * g1.y + xv[6] * g1.z + xv[7] * g1.w;
#pragma unroll
    for (int o = 32; o; o >>= 1) p += __shfl_xor(p, o);
    sc[e] = p;
  }
  float m = sc[0];
#pragma unroll
  for (int e = 1; e < 8; ++e) m = fmaxf(m, sc[e]);
  float ssum = 0.f;
#pragma unroll
  for (int e = 0; e < 8; ++e) { sc[e] = expf(sc[e] - m); ssum += sc[e]; }
  float is = 1.f / ssum;
#pragma unroll
  for (int e = 0; e < 8; ++e) sc[e] *= is;
  int e0 = 0; float v0s = sc[0];
#pragma unroll
  for (int e = 1; e < 8; ++e) if (sc[e] > v0s) { v0s = sc[e]; e0 = e; }
  int e1 = -1; float v1s = -1.f;
#pragma unroll
  for (int e = 0; e < 8; ++e) if (e != e0 && sc[e] > v1s) { v1s = sc[e]; e1 = e; }
  if (lane == 0) {
#pragma unroll
    for (int e = 0; e < 8; ++e) scores[t * 8 + e] = sc[e];
    float d = v0s + v1s + 1e-20f;
    topw[t * 2] = v0s / d; topw[t * 2 + 1] = v1s / d;
    topidx[t * 2] = e0; topidx[t * 2 + 1] = e1;
  }
}

// ---- fused: block 0 = scatter, blocks 1.. = transpose (64x64 tiles, 128B writes) ----
__global__ __launch_bounds__(256) void scatter_transpose_kernel(
    const int* __restrict__ topidx, const float* __restrict__ scores,
    int* __restrict__ pairTok, int* __restrict__ inv,
    int* __restrict__ tileSeg, float* __restrict__ auxout,
    const float* __restrict__ Wg, const float* __restrict__ Wu, const float* __restrict__ Wd,
    const float* __restrict__ Wgs, const float* __restrict__ Wus, const float* __restrict__ Wds,
    u16* __restrict__ Wgt, u16* __restrict__ Wut, u16* __restrict__ Wdt,
    u16* __restrict__ Wgst, u16* __restrict__ Wust, u16* __restrict__ Wdst) {
  __shared__ float tile[64][65];
  __shared__ int cnt[8], offs[8], cur[8];
  __shared__ float partS[256];
  __shared__ int partC[256];
  int tid = threadIdx.x;
  if (blockIdx.x == 0) {
    // ---------------- scatter (256-thread version) ----------------
    if (tid < 8) { cnt[tid] = 0; cur[tid] = 0; }
    __syncthreads();
    for (int p = tid; p < PADCAP; p += 256) pairTok[p] = 0;
    for (int p = tid; p < NPAIRS; p += 256) atomicAdd(&cnt[topidx[p]], 1);
    __syncthreads();
    if (tid == 0) {
      int run = 0;
      for (int e = 0; e < 8; ++e) {
        offs[e] = run;
        run += ((cnt[e] + 127) >> 7) << 7;   // pad each segment to mult of 128
      }
      int RT = run >> 7;
      for (int mt = 0; mt < 56; ++mt) {
        int sgv;
        if (mt >= 40) sgv = 8;               // shared-expert tiles
        else if (mt >= RT) sgv = -1;         // gap
        else {
          sgv = 0;
          for (int e = 7; e >= 1; --e) if (mt >= (offs[e] >> 7)) { sgv = e; break; }
        }
        tileSeg[mt] = sgv;
      }
    }
    __syncthreads();
    for (int p = tid; p < NPAIRS; p += 256) {
      int e = topidx[p];
      int pos = offs[e] + atomicAdd(&cur[e], 1);
      pairTok[pos] = p >> 1;
      inv[p] = pos;
    }
    // aux loss (deterministic reduction)
    int c = tid & 15, g = tid >> 4;
    int b = c >> 3, e = c & 7;
    float ls = 0.f; int lc = 0;
    for (int jj = 0; jj < 64; ++jj) {
      int t = b * 1024 + (g + jj * 16);
      lc += (topidx[t * 2] == e) + (topidx[t * 2 + 1] == e);
      ls += scores[t * 8 + e];
    }
    partS[c * 16 + g] = ls; partC[c * 16 + g] = lc;
    __syncthreads();
    if (tid == 0) {
      float aux = 0.f;
      for (int cc = 0; cc < 16; ++cc) {
        float S = 0.f; int C = 0;
        for (int gg = 0; gg < 16; ++gg) { S += partS[cc * 16 + gg]; C += partC[cc * 16 + gg]; }
        aux += ((float)C / 256.0f) * (S / 1024.0f);
      }
      *auxout = aux * 0.5f * 0.1f;
    }
    return;
  }
  // ---------------- transpose+cast, 64r x 64c tiles, full-line writes ----------------
  int bx = blockIdx.x - 1;
  int slab = bx / 176;
  int t = bx % 176;
  const float* src; u16* dst; int R, C;
  if (slab < 8)       { R = 512;  C = 1408; src = Wg + (size_t)slab * R * C;        dst = Wgt + (size_t)slab * R * C; }
  else if (slab < 16) { R = 512;  C = 1408; src = Wu + (size_t)(slab - 8) * R * C;  dst = Wut + (size_t)(slab - 8) * R * C; }
  else if (slab < 24) { R = 1408; C = 512;  src = Wd + (size_t)(slab - 16) * R * C; dst = Wdt + (size_t)(slab - 16) * R * C; }
  else if (slab == 24){ R = 512;  C = 1408; src = Wgs; dst = Wgst; }
  else if (slab == 25){ R = 512;  C = 1408; src = Wus; dst = Wust; }
  else                { R = 1408; C = 512;  src = Wds; dst = Wdst; }
  int C64 = C >> 6;
  int c0 = (t % C64) * 64, r0 = (t / C64) * 64;
  // read: 4 passes of 16 rows; lane (tid&15) covers 64 cols via float4
  int cf = tid & 15, rr = tid >> 4;
#pragma unroll
  for (int it = 0; it < 4; ++it) {
    int r = rr + it * 16;
    float4 v = *(const float4*)(src + (size_t)(r0 + r) * C + c0 + cf * 4);
    tile[r][cf * 4 + 0] = v.x; tile[r][cf * 4 + 1] = v.y;
    tile[r][cf * 4 + 2] = v.z; tile[r][cf * 4 + 3] = v.w;
  }
  __syncthreads();
  // write: 8 iters; lane-group g (tid>>5) owns col g+8*it; 32 lanes write 32 row-pairs = 128B
  int l = tid & 31, g = tid >> 5;
#pragma unroll
  for (int it = 0; it < 8; ++it) {
    int cl = g + it * 8;
    uint32_t lo = f2bf(tile[2 * l][cl]);
    uint32_t hi = f2bf(tile[2 * l + 1][cl]);
    *(uint32_t*)(dst + (size_t)(c0 + cl) * R + r0 + 2 * l) = lo | (hi << 16);
  }
}

// --------- GEMM1 (R9 champion): BK=64 single-buffer, swizzled staging, 0 conflicts ---------
// grid 616 = 56 mt x 11 nt; XCD k owns wg [77k, 77(k+1))
__global__ __launch_bounds__(256, 2) void gemm1_kernel(
    const u16* __restrict__ Xg,
    const u16* __restrict__ Wgt, const u16* __restrict__ Wut,
    const u16* __restrict__ Wgst, const u16* __restrict__ Wust,
    const int* __restrict__ pairTok, const int* __restrict__ tileSeg,
    u16* __restrict__ act) {
  int lin = blockIdx.x;
  int wg = (lin & 7) * 77 + (lin >> 3);      // bijective: 616 = 8*77
  int mt = wg % 56;
  int nt = wg / 56;
  int s = tileSeg[mt];
  if (s < 0) return;
  const u16* Bg = (s < 8) ? Wgt + (size_t)s * ID * HD : Wgst;
  const u16* Bu = (s < 8) ? Wut + (size_t)s * ID * HD : Wust;

  __shared__ __align__(16) u16 Al[128 * 64];   // 16KB, rows of 128B, XOR-swizzled
  __shared__ __align__(16) u16 Bgl[128 * 64];
  __shared__ __align__(16) u16 Bul[128 * 64];

  int tid = threadIdx.x;
  int w = tid >> 6, lane = tid & 63;
  int sr = lane >> 3;                      // 0..7
  int schx = (lane & 7) ^ sr;              // pre-swizzled source 16B-chunk
  const u16 *aSrc[4], *bgSrc[4], *buSrc[4];
#pragma unroll
  for (int c = 0; c < 4; ++c) {
    int rloc = w * 32 + c * 8 + sr;
    int grow = mt * 128 + rloc;
    int tok = (s < 8) ? pairTok[grow] : (grow - SHOFF);
    aSrc[c]  = Xg + (size_t)tok * HD + schx * 8;
    int nrow = nt * 128 + rloc;
    bgSrc[c] = Bg + (size_t)nrow * HD + schx * 8;
    buSrc[c] = Bu + (size_t)nrow * HD + schx * 8;
  }

  f32x4 accg[4][4], accu[4][4];
  f32x4 zz = {0.f, 0.f, 0.f, 0.f};
#pragma unroll
  for (int i = 0; i < 4; ++i)
#pragma unroll
    for (int j = 0; j < 4; ++j) { accg[i][j] = zz; accu[i][j] = zz; }

  int wm = w >> 1, wn = w & 1;
  int l15 = lane & 15, lh = lane >> 4;

  for (int kt = 0; kt < 8; ++kt) {
    if (kt) __syncthreads();
    int ko = kt * 64;
#pragma unroll
    for (int c = 0; c < 4; ++c) {
      int dby = (w * 32 + c * 8) * 128;
      gll16(aSrc[c] + ko,  (char*)Al  + dby);
      gll16(bgSrc[c] + ko, (char*)Bgl + dby);
      gll16(buSrc[c] + ko, (char*)Bul + dby);
    }
    __syncthreads();
#pragma unroll
    for (int kk = 0; kk < 2; ++kk) {
      bf16x8 a[4], bg[4], bu[4];
#pragma unroll
      for (int i = 0; i < 4; ++i) {
        int row = wm * 64 + i * 16 + l15;
        int by = row * 128 + (((kk * 4 + lh) ^ (row & 7)) << 4);
        a[i] = *(const bf16x8*)((const char*)Al + by);
      }
#pragma unroll
      for (int j = 0; j < 4; ++j) {
        int row = wn * 64 + j * 16 + l15;
        int by = row * 128 + (((kk * 4 + lh) ^ (row & 7)) << 4);
        bg[j] = *(const bf16x8*)((const char*)Bgl + by);
        bu[j] = *(const bf16x8*)((const char*)Bul + by);
      }
#pragma unroll
      for (int i = 0; i < 4; ++i)
#pragma unroll
        for (int j = 0; j < 4; ++j) {
          accg[i][j] = __builtin_amdgcn_mfma_f32_16x16x32_bf16(a[i], bg[j], accg[i][j], 0, 0, 0);
          accu[i][j] = __builtin_amdgcn_mfma_f32_16x16x32_bf16(a[i], bu[j], accu[i][j], 0, 0, 0);
        }
    }
  }
  int base_row = mt * 128;
#pragma unroll
  for (int i = 0; i < 4; ++i)
#pragma unroll
    for (int j = 0; j < 4; ++j)
#pragma unroll
      for (int r = 0; r < 4; ++r) {
        int rl = wm * 64 + i * 16 + lh * 4 + r;
        int col = wn * 64 + j * 16 + l15;
        float gv = accg[i][j][r], uv = accu[i][j][r];
        float av = (gv / (1.f + __expf(-gv))) * uv;
        act[(size_t)(base_row + rl) * ID + nt * 128 + col] = f2bf(av);
      }
}

// --------- GEMM2 (R9 champion): BK=64 single-buffer, split-K=2, swizzled, bf16 out ---------
// grid 448 = 56 mt x 4 nt x 2 kh
__global__ __launch_bounds__(256, 2) void gemm2_kernel(
    const u16* __restrict__ act,
    const u16* __restrict__ Wdt, const u16* __restrict__ Wdst,
    const int* __restrict__ tileSeg, u16* __restrict__ ybuf) {
  int lin = blockIdx.x;
  int wg = (lin & 7) * 56 + (lin >> 3);      // bijective: 448 = 8*56
  int mt = wg % 56;
  int rest = wg / 56;
  int nt = rest & 3, kh = rest >> 2;
  int s = tileSeg[mt];
  if (s < 0) return;
  const u16* B = (s < 8) ? Wdt + (size_t)s * HD * ID : Wdst;  // [512][1408]
  int kbase = kh * 704;
  u16* yb = ybuf + (size_t)kh * TOTROWS * HD;

  __shared__ __align__(16) u16 Al[128 * 64];  // 16KB
  __shared__ __align__(16) u16 Bl[128 * 64];  // 16KB
  int tid = threadIdx.x, w = tid >> 6, lane = tid & 63;
  int sr = lane >> 3;
  int schx = (lane & 7) ^ sr;
  const u16 *aSrc[4], *bSrc[4];
#pragma unroll
  for (int c = 0; c < 4; ++c) {
    int rloc = w * 32 + c * 8 + sr;
    aSrc[c] = act + (size_t)(mt * 128 + rloc) * ID + kbase + schx * 8;
    bSrc[c] = B + (size_t)(nt * 128 + rloc) * ID + kbase + schx * 8;
  }

  f32x4 acc[4][4];
  f32x4 zz = {0.f, 0.f, 0.f, 0.f};
#pragma unroll
  for (int i = 0; i < 4; ++i)
#pragma unroll
    for (int j = 0; j < 4; ++j) acc[i][j] = zz;
  int wm = w >> 1, wn = w & 1, l15 = lane & 15, lh = lane >> 4;

  for (int kt = 0; kt < 11; ++kt) {
    if (kt) __syncthreads();
    int ko = kt * 64;
#pragma unroll
    for (int c = 0; c < 4; ++c) {
      int dby = (w * 32 + c * 8) * 128;
      gll16(aSrc[c] + ko, (char*)Al + dby);
      gll16(bSrc[c] + ko, (char*)Bl + dby);
    }
    __syncthreads();
#pragma unroll
    for (int kk = 0; kk < 2; ++kk) {
      bf16x8 a[4], b[4];
#pragma unroll
      for (int i = 0; i < 4; ++i) {
        int row = wm * 64 + i * 16 + l15;
        int by = row * 128 + (((kk * 4 + lh) ^ (row & 7)) << 4);
        a[i] = *(const bf16x8*)((const char*)Al + by);
      }
#pragma unroll
      for (int j = 0; j < 4; ++j) {
        int row = wn * 64 + j * 16 + l15;
        int by = row * 128 + (((kk * 4 + lh) ^ (row & 7)) << 4);
        b[j] = *(const bf16x8*)((const char*)Bl + by);
      }
#pragma unroll
      for (int i = 0; i < 4; ++i)
#pragma unroll
        for (int j = 0; j < 4; ++j)
          acc[i][j] = __builtin_amdgcn_mfma_f32_16x16x32_bf16(a[i], b[j], acc[i][j], 0, 0, 0);
    }
  }
  int base_row = mt * 128;
#pragma unroll
  for (int i = 0; i < 4; ++i)
#pragma unroll
    for (int j = 0; j < 4; ++j)
#pragma unroll
      for (int r = 0; r < 4; ++r) {
        int rl = wm * 64 + i * 16 + lh * 4 + r;
        int col = wn * 64 + j * 16 + l15;
        yb[(size_t)(base_row + rl) * HD + nt * 128 + col] = f2bf(acc[i][j][r]);
      }
}

// --------- combine: out[t] = w0*y(pair0) + w1*y(pair1) + y(shared), bf16 halves ---------
__global__ void combine_kernel(const u16* __restrict__ ybuf, const float* __restrict__ topw,
                               const int* __restrict__ inv, float* __restrict__ out) {
  int t = blockIdx.x;
  int hd = threadIdx.x;  // 128 threads x 4 elems
  int i0 = inv[t * 2], i1 = inv[t * 2 + 1];
  float w0 = topw[t * 2], w1 = topw[t * 2 + 1];
  const ushort4* y0 = (const ushort4*)ybuf;
  const ushort4* y1 = (const ushort4*)(ybuf + (size_t)TOTROWS * HD);
  ushort4 a0 = y0[(size_t)i0 * 128 + hd], a1 = y1[(size_t)i0 * 128 + hd];
  ushort4 b0 = y0[(size_t)i1 * 128 + hd], b1 = y1[(size_t)i1 * 128 + hd];
  ushort4 c0 = y0[(size_t)(SHOFF + t) * 128 + hd], c1 = y1[(size_t)(SHOFF + t) * 128 + hd];
  float4 o;
  o.x = w0 * (bf2f(a0.x) + bf2f(a1.x)) + w1 * (bf2f(b0.x) + bf2f(b1.x)) + bf2f(c0.x) + bf2f(c1.x);
  o.y = w0 * (bf2f(a0.y) + bf2f(a1.y)) + w1 * (bf2f(b0.y) + bf2f(b1.y)) + bf2f(c0.y) + bf2f(c1.y);
  o.z = w0 * (bf2f(a0.z) + bf2f(a1.z)) + w1 * (bf2f(b0.z) + bf2f(b1.z)) + bf2f(c0.z) + bf2f(c1.z);
  o.w = w0 * (bf2f(a0.w) + bf2f(a1.w)) + w1 * (bf2f(b0.w) + bf2f(b1.w)) + bf2f(c0.w) + bf2f(c1.w);
  ((float4*)out)[(size_t)t * 128 + hd] = o;
}

extern "C" void kernel_launch(void* const* d_in, const int* in_sizes, int n_in,
                              void* d_out, int out_size, void* d_ws, size_t ws_size,
                              hipStream_t stream) {
  const float* x   = (const float*)d_in[0];
  const float* gw  = (const float*)d_in[1];
  const float* Wg  = (const float*)d_in[2];
  const float* Wu  = (const float*)d_in[3];
  const float* Wd  = (const float*)d_in[4];
  const float* Wgs = (const float*)d_in[5];
  const float* Wus = (const float*)d_in[6];
  const float* Wds = (const float*)d_in[7];
  float* out = (float*)d_out;

  if (ws_size < (size_t)96 * 1024 * 1024) return;

  char* ws = (char*)d_ws;
  size_t o = 0;
  auto alloc = [&](size_t bytes) { char* p = ws + o; o += (bytes + 255) & ~(size_t)255; return p; };
  u16* Xg    = (u16*)alloc((size_t)NTOK * HD * 2);
  u16* Wgt   = (u16*)alloc((size_t)8 * ID * HD * 2);
  u16* Wut   = (u16*)alloc((size_t)8 * ID * HD * 2);
  u16* Wdt   = (u16*)alloc((size_t)8 * HD * ID * 2);
  u16* Wgst  = (u16*)alloc((size_t)ID * HD * 2);
  u16* Wust  = (u16*)alloc((size_t)ID * HD * 2);
  u16* Wdst  = (u16*)alloc((size_t)HD * ID * 2);
  u16* act   = (u16*)alloc((size_t)TOTROWS * ID * 2);
  u16* ybuf  = (u16*)alloc((size_t)2 * TOTROWS * HD * 2);
  float* scores = (float*)alloc((size_t)NTOK * 8 * 4);
  float* topw   = (float*)alloc((size_t)NTOK * 2 * 4);
  int* topidx   = (int*)alloc((size_t)NTOK * 2 * 4);
  int* pairTok  = (int*)alloc((size_t)PADCAP * 4);
  int* inv      = (int*)alloc((size_t)NPAIRS * 4);
  int* tileSeg  = (int*)alloc(256);

  gate_kernel<<<NTOK / 4, 256, 0, stream>>>(x, gw, Xg, scores, topw, topidx);
  scatter_transpose_kernel<<<1 + 27 * 176, 256, 0, stream>>>(
      topidx, scores, pairTok, inv, tileSeg, out + (size_t)NTOK * HD,
      Wg, Wu, Wd, Wgs, Wus, Wds, Wgt, Wut, Wdt, Wgst, Wust, Wdst);
  gemm1_kernel<<<616, 256, 0, stream>>>(Xg, Wgt, Wut, Wgst, Wust,
                                        pairTok, tileSeg, act);
  gemm2_kernel<<<448, 256, 0, stream>>>(act, Wdt, Wdst, tileSeg, ybuf);
  combine_kernel<<<NTOK, 128, 0, stream>>>(ybuf, topw, inv, out);
}

// Round 15
// 98.249 us; speedup vs baseline: 1.0064x; 1.0064x over previous
//
#include <hip/hip_runtime.h>
#include <stdint.h>
#include <math.h>

#define HD 512
#define ID 1408
#define NTOK 2048
#define NPAIRS 4096
#define PADCAP 5120
#define SHOFF 5120
#define TOTROWS 7168

typedef unsigned short u16;
typedef __attribute__((ext_vector_type(8))) __bf16 bf16x8;
typedef __attribute__((ext_vector_type(4))) float f32x4;

__device__ __forceinline__ u16 f2bf(float f) {
  union { float f; uint32_t u; } v; v.f = f;
  uint32_t u = v.u;
  u += 0x7FFFu + ((u >> 16) & 1u);   // RNE
  return (u16)(u >> 16);
}
__device__ __forceinline__ float bf2f(u16 u) {
  union { uint32_t u; float f; } v; v.u = ((uint32_t)u) << 16; return v.f;
}

__device__ __forceinline__ void gll16(const void* g, void* l) {
  __builtin_amdgcn_global_load_lds((const __attribute__((address_space(1))) void*)g,
                                   (__attribute__((address_space(3))) void*)l, 16, 0, 0);
}

// ------------- gate: fp32 logits, softmax, top-2; fused x->bf16 cast -------------
__global__ __launch_bounds__(256) void gate_kernel(
    const float* __restrict__ x, const float* __restrict__ gw,
    u16* __restrict__ xg, float* __restrict__ scores,
    float* __restrict__ topw, int* __restrict__ topidx) {
  int t = blockIdx.x * 4 + (threadIdx.x >> 6);
  int lane = threadIdx.x & 63;
  const float4* xp = (const float4*)(x + (size_t)t * HD + lane * 8);
  float4 v0 = xp[0], v1 = xp[1];
  float xv[8] = {v0.x, v0.y, v0.z, v0.w, v1.x, v1.y, v1.z, v1.w};
  ushort4 o0, o1;
  o0.x = f2bf(xv[0]); o0.y = f2bf(xv[1]); o0.z = f2bf(xv[2]); o0.w = f2bf(xv[3]);
  o1.x = f2bf(xv[4]); o1.y = f2bf(xv[5]); o1.z = f2bf(xv[6]); o1.w = f2bf(xv[7]);
  ushort4* xo = (ushort4*)(xg + (size_t)t * HD + lane * 8);
  xo[0] = o0; xo[1] = o1;
  float sc[8];
#pragma unroll
  for (int e = 0; e < 8; ++e) {
    const float4* gp = (const float4*)(gw + e * HD + lane * 8);
    float4 g0 = gp[0], g1 = gp[1];
    float p = xv[0] * g0.x + xv[1] * g0.y + xv[2] * g0.z + xv[3] * g0.w
            + xv[4] * g1.x + xv[5] * g1.y + xv[6] * g1.z + xv[7] * g1.w;
#pragma unroll
    for (int o = 32; o; o >>= 1) p += __shfl_xor(p, o);
    sc[e] = p;
  }
  float m = sc[0];
#pragma unroll
  for (int e = 1; e < 8; ++e) m = fmaxf(m, sc[e]);
  float ssum = 0.f;
#pragma unroll
  for (int e = 0; e < 8; ++e) { sc[e] = expf(sc[e] - m); ssum += sc[e]; }
  float is = 1.f / ssum;
#pragma unroll
  for (int e = 0; e < 8; ++e) sc[e] *= is;
  int e0 = 0; float v0s = sc[0];
#pragma unroll
  for (int e = 1; e < 8; ++e) if (sc[e] > v0s) { v0s = sc[e]; e0 = e; }
  int e1 = -1; float v1s = -1.f;
#pragma unroll
  for (int e = 0; e < 8; ++e) if (e != e0 && sc[e] > v1s) { v1s = sc[e]; e1 = e; }
  if (lane == 0) {
#pragma unroll
    for (int e = 0; e < 8; ++e) scores[t * 8 + e] = sc[e];
    float d = v0s + v1s + 1e-20f;
    topw[t * 2] = v0s / d; topw[t * 2 + 1] = v1s / d;
    topidx[t * 2] = e0; topidx[t * 2 + 1] = e1;
  }
}

// ---- fused: block 0 = scatter; blocks 1.. = transpose (column-band blocks,
//      dense per-block output regions, reg-dbuf chunk pipeline) ----
__global__ __launch_bounds__(256) void scatter_transpose_kernel(
    const int* __restrict__ topidx, const float* __restrict__ scores,
    int* __restrict__ pairTok, int* __restrict__ inv,
    int* __restrict__ tileSeg, float* __restrict__ auxout,
    const float* __restrict__ Wg, const float* __restrict__ Wu, const float* __restrict__ Wd,
    const float* __restrict__ Wgs, const float* __restrict__ Wus, const float* __restrict__ Wds,
    u16* __restrict__ Wgt, u16* __restrict__ Wut, u16* __restrict__ Wdt,
    u16* __restrict__ Wgst, u16* __restrict__ Wust, u16* __restrict__ Wdst) {
  __shared__ float tile[64][65];
  __shared__ int cnt[8], offs[8], cur[8];
  __shared__ float partS[256];
  __shared__ int partC[256];
  int tid = threadIdx.x;
  if (blockIdx.x == 0) {
    // ---------------- scatter (256-thread version) ----------------
    if (tid < 8) { cnt[tid] = 0; cur[tid] = 0; }
    __syncthreads();
    for (int p = tid; p < PADCAP; p += 256) pairTok[p] = 0;
    for (int p = tid; p < NPAIRS; p += 256) atomicAdd(&cnt[topidx[p]], 1);
    __syncthreads();
    if (tid == 0) {
      int run = 0;
      for (int e = 0; e < 8; ++e) {
        offs[e] = run;
        run += ((cnt[e] + 127) >> 7) << 7;   // pad each segment to mult of 128
      }
      int RT = run >> 7;
      for (int mt = 0; mt < 56; ++mt) {
        int sgv;
        if (mt >= 40) sgv = 8;               // shared-expert tiles
        else if (mt >= RT) sgv = -1;         // gap
        else {
          sgv = 0;
          for (int e = 7; e >= 1; --e) if (mt >= (offs[e] >> 7)) { sgv = e; break; }
        }
        tileSeg[mt] = sgv;
      }
    }
    __syncthreads();
    for (int p = tid; p < NPAIRS; p += 256) {
      int e = topidx[p];
      int pos = offs[e] + atomicAdd(&cur[e], 1);
      pairTok[pos] = p >> 1;
      inv[p] = pos;
    }
    // aux loss (deterministic reduction)
    int c = tid & 15, g = tid >> 4;
    int b = c >> 3, e = c & 7;
    float ls = 0.f; int lc = 0;
    for (int jj = 0; jj < 64; ++jj) {
      int t = b * 1024 + (g + jj * 16);
      lc += (topidx[t * 2] == e) + (topidx[t * 2 + 1] == e);
      ls += scores[t * 8 + e];
    }
    partS[c * 16 + g] = ls; partC[c * 16 + g] = lc;
    __syncthreads();
    if (tid == 0) {
      float aux = 0.f;
      for (int cc = 0; cc < 16; ++cc) {
        float S = 0.f; int C = 0;
        for (int gg = 0; gg < 16; ++gg) { S += partS[cc * 16 + gg]; C += partC[cc * 16 + gg]; }
        aux += ((float)C / 256.0f) * (S / 1024.0f);
      }
      *auxout = aux * 0.5f * 0.1f;
    }
    return;
  }
  // ---------------- transpose+cast: block = (slab, 64-col band [, half]) ----------------
  int bx = blockIdx.x - 1;
  const float* src; u16* dst; int R, C, c0, r0base, nch;
  if (bx < 144) {                    // long slabs first: Wd(8) + Wds(1), C=512, R=1408
    int slab = bx / 16;              // 0..8
    int rem = bx % 16;
    int band = rem >> 1, half = rem & 1;
    R = 1408; C = 512;
    src = (slab < 8) ? Wd + (size_t)slab * (size_t)R * C : Wds;
    dst = (slab < 8) ? Wdt + (size_t)slab * (size_t)R * C : Wdst;
    c0 = band * 64; r0base = half * 704; nch = 11;
  } else {                           // Wg(8)+Wu(8)+Wgs+Wus, C=1408, R=512
    int b2 = bx - 144;
    int slab = b2 / 22;              // 0..17
    int band = b2 % 22;
    R = 512; C = 1408;
    if (slab < 8)       { src = Wg + (size_t)slab * (size_t)R * C;       dst = Wgt + (size_t)slab * (size_t)R * C; }
    else if (slab < 16) { src = Wu + (size_t)(slab - 8) * (size_t)R * C; dst = Wut + (size_t)(slab - 8) * (size_t)R * C; }
    else if (slab == 16){ src = Wgs; dst = Wgst; }
    else                { src = Wus; dst = Wust; }
    c0 = band * 64; r0base = 0; nch = 8;
  }
  int cf = tid & 15, rr = tid >> 4;  // read: 16 lanes x float4 = 64 cols; 16 rows/pass
  int colw = tid >> 3, kc = tid & 7; // write: lanes 0-7 = one col's 8 chunks (128B)
  float4 rv[4];
  auto LOAD = [&](int ch) {
    int r0 = r0base + ch * 64;
#pragma unroll
    for (int p = 0; p < 4; ++p)
      rv[p] = *(const float4*)(src + (size_t)(r0 + rr + p * 16) * C + c0 + cf * 4);
  };
  LOAD(0);
  for (int ch = 0; ch < nch; ++ch) {
    if (ch) __syncthreads();         // prev writes done reading tile
#pragma unroll
    for (int p = 0; p < 4; ++p) {
      int r = rr + p * 16;
      tile[r][cf * 4 + 0] = rv[p].x; tile[r][cf * 4 + 1] = rv[p].y;
      tile[r][cf * 4 + 2] = rv[p].z; tile[r][cf * 4 + 3] = rv[p].w;
    }
    __syncthreads();
    if (ch + 1 < nch) LOAD(ch + 1);  // issue next chunk's loads under write phase
    int r0 = r0base + ch * 64;
#pragma unroll
    for (int it = 0; it < 2; ++it) {
      int col = it * 32 + colw;
      uint32_t w0 = (uint32_t)f2bf(tile[kc * 8 + 0][col]) | ((uint32_t)f2bf(tile[kc * 8 + 1][col]) << 16);
      uint32_t w1 = (uint32_t)f2bf(tile[kc * 8 + 2][col]) | ((uint32_t)f2bf(tile[kc * 8 + 3][col]) << 16);
      uint32_t w2 = (uint32_t)f2bf(tile[kc * 8 + 4][col]) | ((uint32_t)f2bf(tile[kc * 8 + 5][col]) << 16);
      uint32_t w3 = (uint32_t)f2bf(tile[kc * 8 + 6][col]) | ((uint32_t)f2bf(tile[kc * 8 + 7][col]) << 16);
      uint4 pk = make_uint4(w0, w1, w2, w3);
      *(uint4*)(dst + (size_t)(c0 + col) * R + r0 + kc * 8) = pk;
    }
  }
}

// --------- GEMM1 (R9 champion): BK=64 single-buffer, swizzled staging, 0 conflicts ---------
// grid 616 = 56 mt x 11 nt; XCD k owns wg [77k, 77(k+1))
__global__ __launch_bounds__(256, 2) void gemm1_kernel(
    const u16* __restrict__ Xg,
    const u16* __restrict__ Wgt, const u16* __restrict__ Wut,
    const u16* __restrict__ Wgst, const u16* __restrict__ Wust,
    const int* __restrict__ pairTok, const int* __restrict__ tileSeg,
    u16* __restrict__ act) {
  int lin = blockIdx.x;
  int wg = (lin & 7) * 77 + (lin >> 3);      // bijective: 616 = 8*77
  int mt = wg % 56;
  int nt = wg / 56;
  int s = tileSeg[mt];
  if (s < 0) return;
  const u16* Bg = (s < 8) ? Wgt + (size_t)s * ID * HD : Wgst;
  const u16* Bu = (s < 8) ? Wut + (size_t)s * ID * HD : Wust;

  __shared__ __align__(16) u16 Al[128 * 64];   // 16KB, rows of 128B, XOR-swizzled
  __shared__ __align__(16) u16 Bgl[128 * 64];
  __shared__ __align__(16) u16 Bul[128 * 64];

  int tid = threadIdx.x;
  int w = tid >> 6, lane = tid & 63;
  int sr = lane >> 3;                      // 0..7
  int schx = (lane & 7) ^ sr;              // pre-swizzled source 16B-chunk
  const u16 *aSrc[4], *bgSrc[4], *buSrc[4];
#pragma unroll
  for (int c = 0; c < 4; ++c) {
    int rloc = w * 32 + c * 8 + sr;
    int grow = mt * 128 + rloc;
    int tok = (s < 8) ? pairTok[grow] : (grow - SHOFF);
    aSrc[c]  = Xg + (size_t)tok * HD + schx * 8;
    int nrow = nt * 128 + rloc;
    bgSrc[c] = Bg + (size_t)nrow * HD + schx * 8;
    buSrc[c] = Bu + (size_t)nrow * HD + schx * 8;
  }

  f32x4 accg[4][4], accu[4][4];
  f32x4 zz = {0.f, 0.f, 0.f, 0.f};
#pragma unroll
  for (int i = 0; i < 4; ++i)
#pragma unroll
    for (int j = 0; j < 4; ++j) { accg[i][j] = zz; accu[i][j] = zz; }

  int wm = w >> 1, wn = w & 1;
  int l15 = lane & 15, lh = lane >> 4;

  for (int kt = 0; kt < 8; ++kt) {
    if (kt) __syncthreads();
    int ko = kt * 64;
#pragma unroll
    for (int c = 0; c < 4; ++c) {
      int dby = (w * 32 + c * 8) * 128;
      gll16(aSrc[c] + ko,  (char*)Al  + dby);
      gll16(bgSrc[c] + ko, (char*)Bgl + dby);
      gll16(buSrc[c] + ko, (char*)Bul + dby);
    }
    __syncthreads();
#pragma unroll
    for (int kk = 0; kk < 2; ++kk) {
      bf16x8 a[4], bg[4], bu[4];
#pragma unroll
      for (int i = 0; i < 4; ++i) {
        int row = wm * 64 + i * 16 + l15;
        int by = row * 128 + (((kk * 4 + lh) ^ (row & 7)) << 4);
        a[i] = *(const bf16x8*)((const char*)Al + by);
      }
#pragma unroll
      for (int j = 0; j < 4; ++j) {
        int row = wn * 64 + j * 16 + l15;
        int by = row * 128 + (((kk * 4 + lh) ^ (row & 7)) << 4);
        bg[j] = *(const bf16x8*)((const char*)Bgl + by);
        bu[j] = *(const bf16x8*)((const char*)Bul + by);
      }
#pragma unroll
      for (int i = 0; i < 4; ++i)
#pragma unroll
        for (int j = 0; j < 4; ++j) {
          accg[i][j] = __builtin_amdgcn_mfma_f32_16x16x32_bf16(a[i], bg[j], accg[i][j], 0, 0, 0);
          accu[i][j] = __builtin_amdgcn_mfma_f32_16x16x32_bf16(a[i], bu[j], accu[i][j], 0, 0, 0);
        }
    }
  }
  int base_row = mt * 128;
#pragma unroll
  for (int i = 0; i < 4; ++i)
#pragma unroll
    for (int j = 0; j < 4; ++j)
#pragma unroll
      for (int r = 0; r < 4; ++r) {
        int rl = wm * 64 + i * 16 + lh * 4 + r;
        int col = wn * 64 + j * 16 + l15;
        float gv = accg[i][j][r], uv = accu[i][j][r];
        float av = (gv / (1.f + __expf(-gv))) * uv;
        act[(size_t)(base_row + rl) * ID + nt * 128 + col] = f2bf(av);
      }
}

// --------- GEMM2 (R9 champion): BK=64 single-buffer, split-K=2, swizzled, bf16 out ---------
// grid 448 = 56 mt x 4 nt x 2 kh
__global__ __launch_bounds__(256, 2) void gemm2_kernel(
    const u16* __restrict__ act,
    const u16* __restrict__ Wdt, const u16* __restrict__ Wdst,
    const int* __restrict__ tileSeg, u16* __restrict__ ybuf) {
  int lin = blockIdx.x;
  int wg = (lin & 7) * 56 + (lin >> 3);      // bijective: 448 = 8*56
  int mt = wg % 56;
  int rest = wg / 56;
  int nt = rest & 3, kh = rest >> 2;
  int s = tileSeg[mt];
  if (s < 0) return;
  const u16* B = (s < 8) ? Wdt + (size_t)s * HD * ID : Wdst;  // [512][1408]
  int kbase = kh * 704;
  u16* yb = ybuf + (size_t)kh * TOTROWS * HD;

  __shared__ __align__(16) u16 Al[128 * 64];  // 16KB
  __shared__ __align__(16) u16 Bl[128 * 64];  // 16KB
  int tid = threadIdx.x, w = tid >> 6, lane = tid & 63;
  int sr = lane >> 3;
  int schx = (lane & 7) ^ sr;
  const u16 *aSrc[4], *bSrc[4];
#pragma unroll
  for (int c = 0; c < 4; ++c) {
    int rloc = w * 32 + c * 8 + sr;
    aSrc[c] = act + (size_t)(mt * 128 + rloc) * ID + kbase + schx * 8;
    bSrc[c] = B + (size_t)(nt * 128 + rloc) * ID + kbase + schx * 8;
  }

  f32x4 acc[4][4];
  f32x4 zz = {0.f, 0.f, 0.f, 0.f};
#pragma unroll
  for (int i = 0; i < 4; ++i)
#pragma unroll
    for (int j = 0; j < 4; ++j) acc[i][j] = zz;
  int wm = w >> 1, wn = w & 1, l15 = lane & 15, lh = lane >> 4;

  for (int kt = 0; kt < 11; ++kt) {
    if (kt) __syncthreads();
    int ko = kt * 64;
#pragma unroll
    for (int c = 0; c < 4; ++c) {
      int dby = (w * 32 + c * 8) * 128;
      gll16(aSrc[c] + ko, (char*)Al + dby);
      gll16(bSrc[c] + ko, (char*)Bl + dby);
    }
    __syncthreads();
#pragma unroll
    for (int kk = 0; kk < 2; ++kk) {
      bf16x8 a[4], b[4];
#pragma unroll
      for (int i = 0; i < 4; ++i) {
        int row = wm * 64 + i * 16 + l15;
        int by = row * 128 + (((kk * 4 + lh) ^ (row & 7)) << 4);
        a[i] = *(const bf16x8*)((const char*)Al + by);
      }
#pragma unroll
      for (int j = 0; j < 4; ++j) {
        int row = wn * 64 + j * 16 + l15;
        int by = row * 128 + (((kk * 4 + lh) ^ (row & 7)) << 4);
        b[j] = *(const bf16x8*)((const char*)Bl + by);
      }
#pragma unroll
      for (int i = 0; i < 4; ++i)
#pragma unroll
        for (int j = 0; j < 4; ++j)
          acc[i][j] = __builtin_amdgcn_mfma_f32_16x16x32_bf16(a[i], b[j], acc[i][j], 0, 0, 0);
    }
  }
  int base_row = mt * 128;
#pragma unroll
  for (int i = 0; i < 4; ++i)
#pragma unroll
    for (int j = 0; j < 4; ++j)
#pragma unroll
      for (int r = 0; r < 4; ++r) {
        int rl = wm * 64 + i * 16 + lh * 4 + r;
        int col = wn * 64 + j * 16 + l15;
        yb[(size_t)(base_row + rl) * HD + nt * 128 + col] = f2bf(acc[i][j][r]);
      }
}

// --------- combine: out[t] = w0*y(pair0) + w1*y(pair1) + y(shared), bf16 halves ---------
__global__ void combine_kernel(const u16* __restrict__ ybuf, const float* __restrict__ topw,
                               const int* __restrict__ inv, float* __restrict__ out) {
  int t = blockIdx.x;
  int hd = threadIdx.x;  // 128 threads x 4 elems
  int i0 = inv[t * 2], i1 = inv[t * 2 + 1];
  float w0 = topw[t * 2], w1 = topw[t * 2 + 1];
  const ushort4* y0 = (const ushort4*)ybuf;
  const ushort4* y1 = (const ushort4*)(ybuf + (size_t)TOTROWS * HD);
  ushort4 a0 = y0[(size_t)i0 * 128 + hd], a1 = y1[(size_t)i0 * 128 + hd];
  ushort4 b0 = y0[(size_t)i1 * 128 + hd], b1 = y1[(size_t)i1 * 128 + hd];
  ushort4 c0 = y0[(size_t)(SHOFF + t) * 128 + hd], c1 = y1[(size_t)(SHOFF + t) * 128 + hd];
  float4 o;
  o.x = w0 * (bf2f(a0.x) + bf2f(a1.x)) + w1 * (bf2f(b0.x) + bf2f(b1.x)) + bf2f(c0.x) + bf2f(c1.x);
  o.y = w0 * (bf2f(a0.y) + bf2f(a1.y)) + w1 * (bf2f(b0.y) + bf2f(b1.y)) + bf2f(c0.y) + bf2f(c1.y);
  o.z = w0 * (bf2f(a0.z) + bf2f(a1.z)) + w1 * (bf2f(b0.z) + bf2f(b1.z)) + bf2f(c0.z) + bf2f(c1.z);
  o.w = w0 * (bf2f(a0.w) + bf2f(a1.w)) + w1 * (bf2f(b0.w) + bf2f(b1.w)) + bf2f(c0.w) + bf2f(c1.w);
  ((float4*)out)[(size_t)t * 128 + hd] = o;
}

extern "C" void kernel_launch(void* const* d_in, const int* in_sizes, int n_in,
                              void* d_out, int out_size, void* d_ws, size_t ws_size,
                              hipStream_t stream) {
  const float* x   = (const float*)d_in[0];
  const float* gw  = (const float*)d_in[1];
  const float* Wg  = (const float*)d_in[2];
  const float* Wu  = (const float*)d_in[3];
  const float* Wd  = (const float*)d_in[4];
  const float* Wgs = (const float*)d_in[5];
  const float* Wus = (const float*)d_in[6];
  const float* Wds = (const float*)d_in[7];
  float* out = (float*)d_out;

  if (ws_size < (size_t)96 * 1024 * 1024) return;

  char* ws = (char*)d_ws;
  size_t o = 0;
  auto alloc = [&](size_t bytes) { char* p = ws + o; o += (bytes + 255) & ~(size_t)255; return p; };
  u16* Xg    = (u16*)alloc((size_t)NTOK * HD * 2);
  u16* Wgt   = (u16*)alloc((size_t)8 * ID * HD * 2);
  u16* Wut   = (u16*)alloc((size_t)8 * ID * HD * 2);
  u16* Wdt   = (u16*)alloc((size_t)8 * HD * ID * 2);
  u16* Wgst  = (u16*)alloc((size_t)ID * HD * 2);
  u16* Wust  = (u16*)alloc((size_t)ID * HD * 2);
  u16* Wdst  = (u16*)alloc((size_t)HD * ID * 2);
  u16* act   = (u16*)alloc((size_t)TOTROWS * ID * 2);
  u16* ybuf  = (u16*)alloc((size_t)2 * TOTROWS * HD * 2);
  float* scores = (float*)alloc((size_t)NTOK * 8 * 4);
  float* topw   = (float*)alloc((size_t)NTOK * 2 * 4);
  int* topidx   = (int*)alloc((size_t)NTOK * 2 * 4);
  int* pairTok  = (int*)alloc((size_t)PADCAP * 4);
  int* inv      = (int*)alloc((size_t)NPAIRS * 4);
  int* tileSeg  = (int*)alloc(256);

  gate_kernel<<<NTOK / 4, 256, 0, stream>>>(x, gw, Xg, scores, topw, topidx);
  scatter_transpose_kernel<<<1 + 144 + 396, 256, 0, stream>>>(
      topidx, scores, pairTok, inv, tileSeg, out + (size_t)NTOK * HD,
      Wg, Wu, Wd, Wgs, Wus, Wds, Wgt, Wut, Wdt, Wgst, Wust, Wdst);
  gemm1_kernel<<<616, 256, 0, stream>>>(Xg, Wgt, Wut, Wgst, Wust,
                                        pairTok, tileSeg, act);
  gemm2_kernel<<<448, 256, 0, stream>>>(act, Wdt, Wdst, tileSeg, ybuf);
  combine_kernel<<<NTOK, 128, 0, stream>>>(ybuf, topw, inv, out);
}

// Round 16
// 88.467 us; speedup vs baseline: 1.1177x; 1.1106x over previous
//
#include <hip/hip_runtime.h>
#include <stdint.h>
#include <math.h>

#define HD 512
#define ID 1408
#define NTOK 2048
#define NPAIRS 4096
#define PADCAP 5120
#define SHOFF 5120
#define TOTROWS 7168

typedef unsigned short u16;
typedef __attribute__((ext_vector_type(8))) __bf16 bf16x8;
typedef __attribute__((ext_vector_type(4))) float f32x4;

__device__ __forceinline__ u16 f2bf(float f) {
  union { float f; uint32_t u; } v; v.f = f;
  uint32_t u = v.u;
  u += 0x7FFFu + ((u >> 16) & 1u);   // RNE
  return (u16)(u >> 16);
}
__device__ __forceinline__ float bf2f(u16 u) {
  union { uint32_t u; float f; } v; v.u = ((uint32_t)u) << 16; return v.f;
}

__device__ __forceinline__ void gll16(const void* g, void* l) {
  __builtin_amdgcn_global_load_lds((const __attribute__((address_space(1))) void*)g,
                                   (__attribute__((address_space(3))) void*)l, 16, 0, 0);
}

// ------- gate: fp32 logits, softmax, top-2; fused x->bf16 cast; aux partials -------
__global__ __launch_bounds__(256) void gate_kernel(
    const float* __restrict__ x, const float* __restrict__ gw,
    u16* __restrict__ xg, float* __restrict__ auxS, int* __restrict__ auxC,
    float* __restrict__ topw, int* __restrict__ topidx) {
  __shared__ float lsS[4][8];
  __shared__ int lsC[4][8];
  int w = threadIdx.x >> 6;
  int t = blockIdx.x * 4 + w;
  int lane = threadIdx.x & 63;
  const float4* xp = (const float4*)(x + (size_t)t * HD + lane * 8);
  float4 v0 = xp[0], v1 = xp[1];
  float xv[8] = {v0.x, v0.y, v0.z, v0.w, v1.x, v1.y, v1.z, v1.w};
  ushort4 o0, o1;
  o0.x = f2bf(xv[0]); o0.y = f2bf(xv[1]); o0.z = f2bf(xv[2]); o0.w = f2bf(xv[3]);
  o1.x = f2bf(xv[4]); o1.y = f2bf(xv[5]); o1.z = f2bf(xv[6]); o1.w = f2bf(xv[7]);
  ushort4* xo = (ushort4*)(xg + (size_t)t * HD + lane * 8);
  xo[0] = o0; xo[1] = o1;
  float sc[8];
#pragma unroll
  for (int e = 0; e < 8; ++e) {
    const float4* gp = (const float4*)(gw + e * HD + lane * 8);
    float4 g0 = gp[0], g1 = gp[1];
    float p = xv[0] * g0.x + xv[1] * g0.y + xv[2] * g0.z + xv[3] * g0.w
            + xv[4] * g1.x + xv[5] * g1.y + xv[6] * g1.z + xv[7] * g1.w;
#pragma unroll
    for (int o = 32; o; o >>= 1) p += __shfl_xor(p, o);
    sc[e] = p;
  }
  float m = sc[0];
#pragma unroll
  for (int e = 1; e < 8; ++e) m = fmaxf(m, sc[e]);
  float ssum = 0.f;
#pragma unroll
  for (int e = 0; e < 8; ++e) { sc[e] = expf(sc[e] - m); ssum += sc[e]; }
  float is = 1.f / ssum;
#pragma unroll
  for (int e = 0; e < 8; ++e) sc[e] *= is;
  int e0 = 0; float v0s = sc[0];
#pragma unroll
  for (int e = 1; e < 8; ++e) if (sc[e] > v0s) { v0s = sc[e]; e0 = e; }
  int e1 = -1; float v1s = -1.f;
#pragma unroll
  for (int e = 0; e < 8; ++e) if (e != e0 && sc[e] > v1s) { v1s = sc[e]; e1 = e; }
  if (lane == 0) {
#pragma unroll
    for (int e = 0; e < 8; ++e) {
      lsS[w][e] = sc[e];
      lsC[w][e] = (e == e0) + (e == e1);
    }
    float d = v0s + v1s + 1e-20f;
    topw[t * 2] = v0s / d; topw[t * 2 + 1] = v1s / d;
    topidx[t * 2] = e0; topidx[t * 2 + 1] = e1;
  }
  __syncthreads();
  if (threadIdx.x < 8) {
    int e = threadIdx.x;
    float S = lsS[0][e] + lsS[1][e] + lsS[2][e] + lsS[3][e];
    int C = lsC[0][e] + lsC[1][e] + lsC[2][e] + lsC[3][e];
    auxS[blockIdx.x * 8 + e] = S;
    auxC[blockIdx.x * 8 + e] = C;
  }
}

// ---- fused: block 0 = light scatter (reduce partials, offsets, perm, aux);
//      blocks 1.. = transpose (64x64 tiles, 128B writes) ----
__global__ __launch_bounds__(256) void scatter_transpose_kernel(
    const int* __restrict__ topidx, const float* __restrict__ auxS, const int* __restrict__ auxC,
    int* __restrict__ pairTok, int* __restrict__ inv,
    int* __restrict__ tileSeg, float* __restrict__ auxout,
    const float* __restrict__ Wg, const float* __restrict__ Wu, const float* __restrict__ Wd,
    const float* __restrict__ Wgs, const float* __restrict__ Wus, const float* __restrict__ Wds,
    u16* __restrict__ Wgt, u16* __restrict__ Wut, u16* __restrict__ Wdt,
    u16* __restrict__ Wgst, u16* __restrict__ Wust, u16* __restrict__ Wdst) {
  __shared__ float tile[64][65];
  int tid = threadIdx.x;
  if (blockIdx.x == 0) {
    __shared__ int C16[16][17];
    __shared__ float S16[16][17];
    __shared__ int offs[8], cur[8];
    int c = tid >> 4, gs = tid & 15;   // combo c=(b,e), stripe gs
    int b = c >> 3, e = c & 7;
    int ci = 0; float si = 0.f;
#pragma unroll 4
    for (int j = 0; j < 16; ++j) {
      int g = b * 256 + gs + j * 16;
      ci += auxC[g * 8 + e];
      si += auxS[g * 8 + e];
    }
    C16[c][gs] = ci; S16[c][gs] = si;
    for (int p = tid; p < PADCAP; p += 256) pairTok[p] = 0;
    __syncthreads();
    if (gs == 0) {
      int Ct = 0; float St = 0.f;
#pragma unroll
      for (int j = 0; j < 16; ++j) { Ct += C16[c][j]; St += S16[c][j]; }
      C16[c][16] = Ct; S16[c][16] = St;
    }
    __syncthreads();
    if (tid < 8) cur[tid] = 0;
    if (tid == 0) {
      int run = 0;
      for (int ee = 0; ee < 8; ++ee) {
        int cnt = C16[ee][16] + C16[8 + ee][16];
        offs[ee] = run;
        run += ((cnt + 127) >> 7) << 7;    // pad each segment to mult of 128
      }
      int RT = run >> 7;
      for (int mt = 0; mt < 56; ++mt) {
        int sgv;
        if (mt >= 40) sgv = 8;             // shared-expert tiles
        else if (mt >= RT) sgv = -1;       // gap
        else {
          sgv = 0;
          for (int ee = 7; ee >= 1; --ee) if (mt >= (offs[ee] >> 7)) { sgv = ee; break; }
        }
        tileSeg[mt] = sgv;
      }
      float aux = 0.f;
      for (int cc = 0; cc < 16; ++cc)
        aux += ((float)C16[cc][16] / 256.0f) * (S16[cc][16] / 1024.0f);
      *auxout = aux * 0.05f;
    }
    __syncthreads();
    for (int p = tid; p < NPAIRS; p += 256) {
      int ee = topidx[p];
      int pos = offs[ee] + atomicAdd(&cur[ee], 1);
      pairTok[pos] = p >> 1;
      inv[p] = pos;
    }
    return;
  }
  // ---------------- transpose+cast, 64r x 64c tiles, full-line writes ----------------
  int bx = blockIdx.x - 1;
  int slab = bx / 176;
  int t = bx % 176;
  const float* src; u16* dst; int R, C;
  if (slab < 8)       { R = 512;  C = 1408; src = Wg + (size_t)slab * R * C;        dst = Wgt + (size_t)slab * R * C; }
  else if (slab < 16) { R = 512;  C = 1408; src = Wu + (size_t)(slab - 8) * R * C;  dst = Wut + (size_t)(slab - 8) * R * C; }
  else if (slab < 24) { R = 1408; C = 512;  src = Wd + (size_t)(slab - 16) * R * C; dst = Wdt + (size_t)(slab - 16) * R * C; }
  else if (slab == 24){ R = 512;  C = 1408; src = Wgs; dst = Wgst; }
  else if (slab == 25){ R = 512;  C = 1408; src = Wus; dst = Wust; }
  else                { R = 1408; C = 512;  src = Wds; dst = Wdst; }
  int C64 = C >> 6;
  int c0 = (t % C64) * 64, r0 = (t / C64) * 64;
  int cf = tid & 15, rr = tid >> 4;
#pragma unroll
  for (int it = 0; it < 4; ++it) {
    int r = rr + it * 16;
    float4 v = *(const float4*)(src + (size_t)(r0 + r) * C + c0 + cf * 4);
    tile[r][cf * 4 + 0] = v.x; tile[r][cf * 4 + 1] = v.y;
    tile[r][cf * 4 + 2] = v.z; tile[r][cf * 4 + 3] = v.w;
  }
  __syncthreads();
  int l = tid & 31, g = tid >> 5;
#pragma unroll
  for (int it = 0; it < 8; ++it) {
    int cl = g + it * 8;
    uint32_t lo = f2bf(tile[2 * l][cl]);
    uint32_t hi = f2bf(tile[2 * l + 1][cl]);
    *(uint32_t*)(dst + (size_t)(c0 + cl) * R + r0 + 2 * l) = lo | (hi << 16);
  }
}

// --------- GEMM1 (R9 champion): BK=64 single-buffer, swizzled staging, 0 conflicts ---------
// grid 616 = 56 mt x 11 nt; XCD k owns wg [77k, 77(k+1))
__global__ __launch_bounds__(256, 2) void gemm1_kernel(
    const u16* __restrict__ Xg,
    const u16* __restrict__ Wgt, const u16* __restrict__ Wut,
    const u16* __restrict__ Wgst, const u16* __restrict__ Wust,
    const int* __restrict__ pairTok, const int* __restrict__ tileSeg,
    u16* __restrict__ act) {
  int lin = blockIdx.x;
  int wg = (lin & 7) * 77 + (lin >> 3);      // bijective: 616 = 8*77
  int mt = wg % 56;
  int nt = wg / 56;
  int s = tileSeg[mt];
  if (s < 0) return;
  const u16* Bg = (s < 8) ? Wgt + (size_t)s * ID * HD : Wgst;
  const u16* Bu = (s < 8) ? Wut + (size_t)s * ID * HD : Wust;

  __shared__ __align__(16) u16 Al[128 * 64];   // 16KB, rows of 128B, XOR-swizzled
  __shared__ __align__(16) u16 Bgl[128 * 64];
  __shared__ __align__(16) u16 Bul[128 * 64];

  int tid = threadIdx.x;
  int w = tid >> 6, lane = tid & 63;
  int sr = lane >> 3;                      // 0..7
  int schx = (lane & 7) ^ sr;              // pre-swizzled source 16B-chunk
  const u16 *aSrc[4], *bgSrc[4], *buSrc[4];
#pragma unroll
  for (int c = 0; c < 4; ++c) {
    int rloc = w * 32 + c * 8 + sr;
    int grow = mt * 128 + rloc;
    int tok = (s < 8) ? pairTok[grow] : (grow - SHOFF);
    aSrc[c]  = Xg + (size_t)tok * HD + schx * 8;
    int nrow = nt * 128 + rloc;
    bgSrc[c] = Bg + (size_t)nrow * HD + schx * 8;
    buSrc[c] = Bu + (size_t)nrow * HD + schx * 8;
  }

  f32x4 accg[4][4], accu[4][4];
  f32x4 zz = {0.f, 0.f, 0.f, 0.f};
#pragma unroll
  for (int i = 0; i < 4; ++i)
#pragma unroll
    for (int j = 0; j < 4; ++j) { accg[i][j] = zz; accu[i][j] = zz; }

  int wm = w >> 1, wn = w & 1;
  int l15 = lane & 15, lh = lane >> 4;

  for (int kt = 0; kt < 8; ++kt) {
    if (kt) __syncthreads();
    int ko = kt * 64;
#pragma unroll
    for (int c = 0; c < 4; ++c) {
      int dby = (w * 32 + c * 8) * 128;
      gll16(aSrc[c] + ko,  (char*)Al  + dby);
      gll16(bgSrc[c] + ko, (char*)Bgl + dby);
      gll16(buSrc[c] + ko, (char*)Bul + dby);
    }
    __syncthreads();
#pragma unroll
    for (int kk = 0; kk < 2; ++kk) {
      bf16x8 a[4], bg[4], bu[4];
#pragma unroll
      for (int i = 0; i < 4; ++i) {
        int row = wm * 64 + i * 16 + l15;
        int by = row * 128 + (((kk * 4 + lh) ^ (row & 7)) << 4);
        a[i] = *(const bf16x8*)((const char*)Al + by);
      }
#pragma unroll
      for (int j = 0; j < 4; ++j) {
        int row = wn * 64 + j * 16 + l15;
        int by = row * 128 + (((kk * 4 + lh) ^ (row & 7)) << 4);
        bg[j] = *(const bf16x8*)((const char*)Bgl + by);
        bu[j] = *(const bf16x8*)((const char*)Bul + by);
      }
#pragma unroll
      for (int i = 0; i < 4; ++i)
#pragma unroll
        for (int j = 0; j < 4; ++j) {
          accg[i][j] = __builtin_amdgcn_mfma_f32_16x16x32_bf16(a[i], bg[j], accg[i][j], 0, 0, 0);
          accu[i][j] = __builtin_amdgcn_mfma_f32_16x16x32_bf16(a[i], bu[j], accu[i][j], 0, 0, 0);
        }
    }
  }
  int base_row = mt * 128;
#pragma unroll
  for (int i = 0; i < 4; ++i)
#pragma unroll
    for (int j = 0; j < 4; ++j)
#pragma unroll
      for (int r = 0; r < 4; ++r) {
        int rl = wm * 64 + i * 16 + lh * 4 + r;
        int col = wn * 64 + j * 16 + l15;
        float gv = accg[i][j][r], uv = accu[i][j][r];
        float av = (gv / (1.f + __expf(-gv))) * uv;
        act[(size_t)(base_row + rl) * ID + nt * 128 + col] = f2bf(av);
      }
}

// --------- GEMM2 (R9 champion): BK=64 single-buffer, split-K=2, swizzled, bf16 out ---------
// grid 448 = 56 mt x 4 nt x 2 kh
__global__ __launch_bounds__(256, 2) void gemm2_kernel(
    const u16* __restrict__ act,
    const u16* __restrict__ Wdt, const u16* __restrict__ Wdst,
    const int* __restrict__ tileSeg, u16* __restrict__ ybuf) {
  int lin = blockIdx.x;
  int wg = (lin & 7) * 56 + (lin >> 3);      // bijective: 448 = 8*56
  int mt = wg % 56;
  int rest = wg / 56;
  int nt = rest & 3, kh = rest >> 2;
  int s = tileSeg[mt];
  if (s < 0) return;
  const u16* B = (s < 8) ? Wdt + (size_t)s * HD * ID : Wdst;  // [512][1408]
  int kbase = kh * 704;
  u16* yb = ybuf + (size_t)kh * TOTROWS * HD;

  __shared__ __align__(16) u16 Al[128 * 64];  // 16KB
  __shared__ __align__(16) u16 Bl[128 * 64];  // 16KB
  int tid = threadIdx.x, w = tid >> 6, lane = tid & 63;
  int sr = lane >> 3;
  int schx = (lane & 7) ^ sr;
  const u16 *aSrc[4], *bSrc[4];
#pragma unroll
  for (int c = 0; c < 4; ++c) {
    int rloc = w * 32 + c * 8 + sr;
    aSrc[c] = act + (size_t)(mt * 128 + rloc) * ID + kbase + schx * 8;
    bSrc[c] = B + (size_t)(nt * 128 + rloc) * ID + kbase + schx * 8;
  }

  f32x4 acc[4][4];
  f32x4 zz = {0.f, 0.f, 0.f, 0.f};
#pragma unroll
  for (int i = 0; i < 4; ++i)
#pragma unroll
    for (int j = 0; j < 4; ++j) acc[i][j] = zz;
  int wm = w >> 1, wn = w & 1, l15 = lane & 15, lh = lane >> 4;

  for (int kt = 0; kt < 11; ++kt) {
    if (kt) __syncthreads();
    int ko = kt * 64;
#pragma unroll
    for (int c = 0; c < 4; ++c) {
      int dby = (w * 32 + c * 8) * 128;
      gll16(aSrc[c] + ko, (char*)Al + dby);
      gll16(bSrc[c] + ko, (char*)Bl + dby);
    }
    __syncthreads();
#pragma unroll
    for (int kk = 0; kk < 2; ++kk) {
      bf16x8 a[4], b[4];
#pragma unroll
      for (int i = 0; i < 4; ++i) {
        int row = wm * 64 + i * 16 + l15;
        int by = row * 128 + (((kk * 4 + lh) ^ (row & 7)) << 4);
        a[i] = *(const bf16x8*)((const char*)Al + by);
      }
#pragma unroll
      for (int j = 0; j < 4; ++j) {
        int row = wn * 64 + j * 16 + l15;
        int by = row * 128 + (((kk * 4 + lh) ^ (row & 7)) << 4);
        b[j] = *(const bf16x8*)((const char*)Bl + by);
      }
#pragma unroll
      for (int i = 0; i < 4; ++i)
#pragma unroll
        for (int j = 0; j < 4; ++j)
          acc[i][j] = __builtin_amdgcn_mfma_f32_16x16x32_bf16(a[i], b[j], acc[i][j], 0, 0, 0);
    }
  }
  int base_row = mt * 128;
#pragma unroll
  for (int i = 0; i < 4; ++i)
#pragma unroll
    for (int j = 0; j < 4; ++j)
#pragma unroll
      for (int r = 0; r < 4; ++r) {
        int rl = wm * 64 + i * 16 + lh * 4 + r;
        int col = wn * 64 + j * 16 + l15;
        yb[(size_t)(base_row + rl) * HD + nt * 128 + col] = f2bf(acc[i][j][r]);
      }
}

// --------- combine: out[t] = w0*y(pair0) + w1*y(pair1) + y(shared), bf16 halves ---------
__global__ void combine_kernel(const u16* __restrict__ ybuf, const float* __restrict__ topw,
                               const int* __restrict__ inv, float* __restrict__ out) {
  int t = blockIdx.x;
  int hd = threadIdx.x;  // 128 threads x 4 elems
  int i0 = inv[t * 2], i1 = inv[t * 2 + 1];
  float w0 = topw[t * 2], w1 = topw[t * 2 + 1];
  const ushort4* y0 = (const ushort4*)ybuf;
  const ushort4* y1 = (const ushort4*)(ybuf + (size_t)TOTROWS * HD);
  ushort4 a0 = y0[(size_t)i0 * 128 + hd], a1 = y1[(size_t)i0 * 128 + hd];
  ushort4 b0 = y0[(size_t)i1 * 128 + hd], b1 = y1[(size_t)i1 * 128 + hd];
  ushort4 c0 = y0[(size_t)(SHOFF + t) * 128 + hd], c1 = y1[(size_t)(SHOFF + t) * 128 + hd];
  float4 o;
  o.x = w0 * (bf2f(a0.x) + bf2f(a1.x)) + w1 * (bf2f(b0.x) + bf2f(b1.x)) + bf2f(c0.x) + bf2f(c1.x);
  o.y = w0 * (bf2f(a0.y) + bf2f(a1.y)) + w1 * (bf2f(b0.y) + bf2f(b1.y)) + bf2f(c0.y) + bf2f(c1.y);
  o.z = w0 * (bf2f(a0.z) + bf2f(a1.z)) + w1 * (bf2f(b0.z) + bf2f(b1.z)) + bf2f(c0.z) + bf2f(c1.z);
  o.w = w0 * (bf2f(a0.w) + bf2f(a1.w)) + w1 * (bf2f(b0.w) + bf2f(b1.w)) + bf2f(c0.w) + bf2f(c1.w);
  ((float4*)out)[(size_t)t * 128 + hd] = o;
}

extern "C" void kernel_launch(void* const* d_in, const int* in_sizes, int n_in,
                              void* d_out, int out_size, void* d_ws, size_t ws_size,
                              hipStream_t stream) {
  const float* x   = (const float*)d_in[0];
  const float* gw  = (const float*)d_in[1];
  const float* Wg  = (const float*)d_in[2];
  const float* Wu  = (const float*)d_in[3];
  const float* Wd  = (const float*)d_in[4];
  const float* Wgs = (const float*)d_in[5];
  const float* Wus = (const float*)d_in[6];
  const float* Wds = (const float*)d_in[7];
  float* out = (float*)d_out;

  if (ws_size < (size_t)96 * 1024 * 1024) return;

  char* ws = (char*)d_ws;
  size_t o = 0;
  auto alloc = [&](size_t bytes) { char* p = ws + o; o += (bytes + 255) & ~(size_t)255; return p; };
  u16* Xg    = (u16*)alloc((size_t)NTOK * HD * 2);
  u16* Wgt   = (u16*)alloc((size_t)8 * ID * HD * 2);
  u16* Wut   = (u16*)alloc((size_t)8 * ID * HD * 2);
  u16* Wdt   = (u16*)alloc((size_t)8 * HD * ID * 2);
  u16* Wgst  = (u16*)alloc((size_t)ID * HD * 2);
  u16* Wust  = (u16*)alloc((size_t)ID * HD * 2);
  u16* Wdst  = (u16*)alloc((size_t)HD * ID * 2);
  u16* act   = (u16*)alloc((size_t)TOTROWS * ID * 2);
  u16* ybuf  = (u16*)alloc((size_t)2 * TOTROWS * HD * 2);
  float* auxS   = (float*)alloc((size_t)512 * 8 * 4);
  int* auxC     = (int*)alloc((size_t)512 * 8 * 4);
  float* topw   = (float*)alloc((size_t)NTOK * 2 * 4);
  int* topidx   = (int*)alloc((size_t)NTOK * 2 * 4);
  int* pairTok  = (int*)alloc((size_t)PADCAP * 4);
  int* inv      = (int*)alloc((size_t)NPAIRS * 4);
  int* tileSeg  = (int*)alloc(256);

  gate_kernel<<<NTOK / 4, 256, 0, stream>>>(x, gw, Xg, auxS, auxC, topw, topidx);
  scatter_transpose_kernel<<<1 + 27 * 176, 256, 0, stream>>>(
      topidx, auxS, auxC, pairTok, inv, tileSeg, out + (size_t)NTOK * HD,
      Wg, Wu, Wd, Wgs, Wus, Wds, Wgt, Wut, Wdt, Wgst, Wust, Wdst);
  gemm1_kernel<<<616, 256, 0, stream>>>(Xg, Wgt, Wut, Wgst, Wust,
                                        pairTok, tileSeg, act);
  gemm2_kernel<<<448, 256, 0, stream>>>(act, Wdt, Wdst, tileSeg, ybuf);
  combine_kernel<<<NTOK, 128, 0, stream>>>(ybuf, topw, inv, out);
}